// Round 1
// baseline (247.989 us; speedup 1.0000x reference)
//
#include <hip/hip_runtime.h>
#include <hip/hip_bf16.h>

#define D_MODEL 4096
#define NTOK    8192   // B*S = 4*2048
#define SEQ     2048

typedef short bf16x8 __attribute__((ext_vector_type(8)));  // 8 bf16 in 4 VGPRs
typedef float f32x4  __attribute__((ext_vector_type(4)));

__device__ __forceinline__ short f2bf(float x) {
  __hip_bfloat16 h = __float2bfloat16(x);
  return *reinterpret_cast<short*>(&h);
}
__device__ __forceinline__ float bfs2f(unsigned short u) {
  unsigned int x = ((unsigned int)u) << 16;
  float f;
  __builtin_memcpy(&f, &x, 4);
  return f;
}
__device__ __forceinline__ float bf2f(const void* p, size_t i) {
  return bfs2f(((const unsigned short*)p)[i]);
}

// ---------------------------------------------------------------------------
// Wave-level dtype sniff (ported from the old sniff_k kernel; each consumer
// wave computes the flag it needs — saves a dispatch + dependency stall).
// Returns 1 -> treat as bf16[], 0 -> treat as float[]. Wave-uniform result.
// n = element count if bf16 (i.e., short count).
// ---------------------------------------------------------------------------
__device__ __forceinline__ int sniff_wave(const unsigned short* p, int n) {
  int lane = threadIdx.x & 63;
  int S = n / 2 < 64 ? n / 2 : 64;
  bool act = lane < S;
  unsigned short ve = 0, vo = 0;
  if (act) { ve = p[2 * lane]; vo = p[2 * lane + 1]; }
  int ee = (ve >> 7) & 0xFF, eo = (vo >> 7) & 0xFF;
  bool ve_band   = (ve == 0) || (ve == 0x8000) || (ee >= 96 && ee <= 141);
  bool vo_bandnz = (vo != 0) && (vo != 0x8000) && (eo >= 96 && eo <= 141);
  int zp = __popcll(__ballot(act && ve == 0 && vo == 0));
  int ob = __popcll(__ballot(act && ve == 0 && vo_bandnz));
  int eb = __popcll(__ballot(act && ve_band));
  if (zp == S) return 1;
  if (4 * ob >= 3 * S) return 0;   // f32 storage of bf16-rounded values
  if (4 * eb >= 3 * S) return 1;   // true bf16
  return 0;                        // raw f32
}

__device__ __forceinline__ float decode_lam(const void* lamp) {
  unsigned short l0 = *(const unsigned short*)lamp;
  int le = (l0 >> 7) & 0xFF;
  if (l0 != 0 && l0 != 0x8000 && le >= 96 && le <= 141)
    return bfs2f(l0);
  return *(const float*)lamp;
}
__device__ __forceinline__ float decode_b2(const void* p) {
  unsigned short c0 = *(const unsigned short*)p;
  int ce = (c0 >> 7) & 0xFF;
  if (c0 == 0) return 0.0f;
  if (c0 != 0x8000 && ce >= 96 && ce <= 141)
    return bfs2f(c0);
  return *(const float*)p;
}

// ---------------------------------------------------------------------------
// Kernel 1: fold W_fiber into W1 -> W1_eff[64][4096] bf16. Vectorized:
// 4 k's per thread per iter -> 17 vector loads vs 68 scalar (4x fewer issues).
// ---------------------------------------------------------------------------
__global__ __launch_bounds__(256) void fold_w1(const void* __restrict__ W1v,
                                               const void* __restrict__ Wfv,
                                               short* __restrict__ W1eff) {
  int n = blockIdx.x;  // 0..63
  int fw1 = sniff_wave((const unsigned short*)W1v, 64 * 4112);
  int fwf = sniff_wave((const unsigned short*)Wfv, 16 * D_MODEL);
  __shared__ float w1b[16];
  if (threadIdx.x < 16) {
    size_t idx = (size_t)n * 4112 + 4096 + threadIdx.x;
    w1b[threadIdx.x] = fw1 ? bf2f(W1v, idx) : ((const float*)W1v)[idx];
  }
  __syncthreads();
  for (int it = 0; it < 4; ++it) {
    int k0 = it * 1024 + threadIdx.x * 4;
    size_t idx = (size_t)n * 4112 + k0;
    float v0, v1, v2, v3;
    if (fw1) {
      ushort4 u = *(const ushort4*)((const unsigned short*)W1v + idx);
      v0 = bfs2f(u.x); v1 = bfs2f(u.y); v2 = bfs2f(u.z); v3 = bfs2f(u.w);
    } else {
      float4 f = *(const float4*)((const float*)W1v + idx);
      v0 = f.x; v1 = f.y; v2 = f.z; v3 = f.w;
    }
#pragma unroll
    for (int f = 0; f < 16; ++f) {
      size_t wi = (size_t)f * D_MODEL + k0;
      float w0, w1_, w2_, w3_;
      if (fwf) {
        ushort4 u = *(const ushort4*)((const unsigned short*)Wfv + wi);
        w0 = bfs2f(u.x); w1_ = bfs2f(u.y); w2_ = bfs2f(u.z); w3_ = bfs2f(u.w);
      } else {
        float4 fv = *(const float4*)((const float*)Wfv + wi);
        w0 = fv.x; w1_ = fv.y; w2_ = fv.z; w3_ = fv.w;
      }
      float s = w1b[f];
      v0 += s * w0; v1 += s * w1_; v2 += s * w2_; v3 += s * w3_;
    }
    ushort4 o;
    o.x = (unsigned short)f2bf(v0); o.y = (unsigned short)f2bf(v1);
    o.z = (unsigned short)f2bf(v2); o.w = (unsigned short)f2bf(v3);
    *(ushort4*)(W1eff + (size_t)n * D_MODEL + k0) = o;
  }
}

// ---------------------------------------------------------------------------
// Kernel 2: fused GEMM + epilogue. Grid 512 blocks x 512 thr (8 waves),
// 2 blocks/CU (LDS 68 KB). Block t owns tokens [t*16, +16) over FULL K=4096:
// wave w -> (wc = w&3: col tile 16*wc, kc = w>>2: K-half within each chunk).
// B (=W1eff, 512 KB, L2-resident per XCD) staged chunk-by-chunk (64x512 bf16
// = 64 KB) through the SAME XOR-swizzled LDS layout as the previous split-K
// kernel: slot16B[kb16][n ^ (kb16&7)]; fragment reads are the proven
// conflict-free b128 pattern. A double-buffered in regs across chunks
// (issue next chunk's 8x16B before the stage barrier -> HBM latency hidden
// under B staging). No split-K partials, no second kernel: kc halves reduced
// through a 4.3 KB LDS tile, then bias + exact GELU + dot(W2) + softplus
// fused in-block -> delta[16] written directly.
// MFMA 16x16x32 bf16: A[m=lane&15][k=8*(lane>>4)+j]; C: col=lane&15,
// row=(lane>>4)*4+reg (m89/m91-verified, carried over unchanged).
// ---------------------------------------------------------------------------
__device__ __forceinline__ void stage_chunk(short* Bs, const short* __restrict__ B_,
                                            int c, int w, int lane) {
#pragma unroll
  for (int i = 0; i < 8; ++i) {
    int n = w + i * 8;          // 0..63 (wave-uniform row, lanes sweep 1 KB)
    bf16x8 v = *(const bf16x8*)(B_ + (size_t)n * D_MODEL + c * 512 + lane * 8);
    *(bf16x8*)(Bs + lane * 512 + ((n ^ (lane & 7)) * 8)) = v;
  }
}

__global__ __launch_bounds__(512, 4) void gemm_fused(const void* __restrict__ hid,
                                                     const short* __restrict__ B_,
                                                     const void* __restrict__ b1,
                                                     const void* __restrict__ w2,
                                                     const void* __restrict__ b2,
                                                     float* __restrict__ delta) {
  int t = blockIdx.x;                 // token tile 0..511
  int w = threadIdx.x >> 6, lane = threadIdx.x & 63;
  int wc = w & 3, kc = w >> 2;
  int m = lane & 15, kg = lane >> 4;

  __shared__ short Bs[64 * 512];      // 64 KB, swizzled 16B slots
  __shared__ float red[16][68];       // kc-reduce + epilogue scratch (pitch 68: conflict-free)

  int fhid = sniff_wave((const unsigned short*)hid, NTOK * D_MODEL);

  f32x4 acc = {0.f, 0.f, 0.f, 0.f};
  size_t abase = (size_t)(t * 16 + m) * D_MODEL + kc * 256 + kg * 8;

  if (fhid) {  // hidden bf16 (confirmed path)
    const short* Ap = (const short*)hid + abase;
    bf16x8 areg[2][8];
#pragma unroll
    for (int s = 0; s < 8; ++s) areg[0][s] = *(const bf16x8*)(Ap + s * 32);
#pragma unroll
    for (int c = 0; c < 8; ++c) {
      __syncthreads();                // Bs free (prev chunk's reads done)
      if (c < 7) {
#pragma unroll
        for (int s = 0; s < 8; ++s)   // issue next A chunk first (HBM) ...
          areg[(c + 1) & 1][s] = *(const bf16x8*)(Ap + (c + 1) * 512 + s * 32);
      }
      stage_chunk(Bs, B_, c, w, lane);  // ... overlap with B staging (L2)
      __syncthreads();
#pragma unroll
      for (int s = 0; s < 8; ++s) {
        int kb16 = kc * 32 + s * 4 + kg;
        bf16x8 b = *(const bf16x8*)(Bs + kb16 * 512 + (((wc * 16 + m) ^ (kb16 & 7)) * 8));
        acc = __builtin_amdgcn_mfma_f32_16x16x32_bf16(areg[c & 1][s], b, acc, 0, 0, 0);
      }
    }
  } else {     // hidden f32 fallback (correctness path)
    const float* Ap = (const float*)hid + abase;
    for (int c = 0; c < 8; ++c) {
      __syncthreads();
      stage_chunk(Bs, B_, c, w, lane);
      __syncthreads();
#pragma unroll
      for (int s = 0; s < 8; ++s) {
        float4 lo = *(const float4*)(Ap + c * 512 + s * 32);
        float4 hi = *(const float4*)(Ap + c * 512 + s * 32 + 4);
        bf16x8 a;
        a[0] = f2bf(lo.x); a[1] = f2bf(lo.y); a[2] = f2bf(lo.z); a[3] = f2bf(lo.w);
        a[4] = f2bf(hi.x); a[5] = f2bf(hi.y); a[6] = f2bf(hi.z); a[7] = f2bf(hi.w);
        int kb16 = kc * 32 + s * 4 + kg;
        bf16x8 b = *(const bf16x8*)(Bs + kb16 * 512 + (((wc * 16 + m) ^ (kb16 & 7)) * 8));
        acc = __builtin_amdgcn_mfma_f32_16x16x32_bf16(a, b, acc, 0, 0, 0);
      }
    }
  }

  // ---- epilogue: kc-reduce, + b1, exact GELU, * W2, per-token sum, softplus ----
  if (kc == 1) {
#pragma unroll
    for (int r = 0; r < 4; ++r) red[kg * 4 + r][wc * 16 + m] = acc[r];
  }
  __syncthreads();
  float b2v = 0.f;
  if (kc == 0) {
    int fb1 = sniff_wave((const unsigned short*)b1, 64);
    int fw2 = sniff_wave((const unsigned short*)w2, 64);
    b2v = decode_b2(b2);
    int col = wc * 16 + m;
    float b1v = fb1 ? bf2f(b1, col) : ((const float*)b1)[col];
    float w2v = fw2 ? bf2f(w2, col) : ((const float*)w2)[col];
#pragma unroll
    for (int r = 0; r < 4; ++r) {
      int tok = kg * 4 + r;
      float s = acc[r] + red[tok][col] + b1v;
      float g = 0.5f * s * (1.0f + erff(s * 0.70710678118654752f));  // exact GELU
      red[tok][col] = g * w2v;
    }
  }
  __syncthreads();
  if (threadIdx.x < 16) {            // wave 0 (kc==0): b2v is live here
    float y = 0.f;
#pragma unroll
    for (int cc = 0; cc < 64; ++cc) y += red[threadIdx.x][cc];
    float x = y + b2v;
    float d = (x > 20.0f) ? x : log1pf(expf(x));  // softplus
    delta[t * 16 + threadIdx.x] = d;
  }
}

// ---------------------------------------------------------------------------
// Kernel 3: causal EMA, gate, field, mean. OUTPUT IS FLOAT32 (mixed tuple
// (bf16,bf16,f32) concatenated by harness -> numpy-promoted f32).
// ---------------------------------------------------------------------------
__global__ __launch_bounds__(256) void ema_out(const float* __restrict__ delta,
                                               const void* __restrict__ lamp,
                                               float* __restrict__ out) {
  int b    = threadIdx.x >> 6;   // batch 0..3
  int lane = threadIdx.x & 63;
  const float alpha = 0.9f;
  float d[32];
  const float* dp = delta + b * SEQ + lane * 32;
  float beta = 0.f, lsum = 0.f;
#pragma unroll
  for (int i = 0; i < 32; ++i) {
    d[i] = dp[i];
    lsum += d[i];
    beta = alpha * beta + 0.1f * d[i];
  }
  float accA = 0.03433683820292512f;  // 0.9^32
  float accB = beta;
  for (int off = 1; off < 64; off <<= 1) {
    float uA = __shfl_up(accA, off, 64);
    float uB = __shfl_up(accB, off, 64);
    if (lane >= off) {
      accB = accB + accA * uB;  // cur o prev
      accA = accA * uA;
    }
  }
  float prev = __shfl_up(accB, 1, 64);
  float h = (lane == 0) ? 0.f : prev;  // carry-in state for this chunk
  float lam = decode_lam(lamp);
#pragma unroll
  for (int i = 0; i < 32; ++i) {
    h = alpha * h + 0.1f * d[i];
    float gate = 1.0f / (1.0f + expf(lam * h));  // sigmoid(-lam*h)
    out[b * SEQ + lane * 32 + i]        = gate;
    out[NTOK + b * SEQ + lane * 32 + i] = h;
  }
#pragma unroll
  for (int off = 32; off >= 1; off >>= 1) lsum += __shfl_xor(lsum, off, 64);
  __shared__ float bs[4];
  if (lane == 0) bs[b] = lsum;
  __syncthreads();
  if (threadIdx.x == 0)
    out[2 * NTOK] = (bs[0] + bs[1] + bs[2] + bs[3]) * (1.0f / 8192.0f);
}

// ---------------------------------------------------------------------------
extern "C" void kernel_launch(void* const* d_in, const int* in_sizes, int n_in,
                              void* d_out, int out_size, void* d_ws, size_t ws_size,
                              hipStream_t stream) {
  const void* hidden = d_in[0];  // [4,2048,4096]
  const void* Wf     = d_in[1];  // [16,4096]
  const void* W1     = d_in[2];  // [64,4112]
  const void* b1     = d_in[3];  // [64]
  const void* W2     = d_in[4];  // [1,64]
  const void* b2     = d_in[5];  // [1]
  const void* lam    = d_in[6];  // [1]
  float* out = (float*)d_out;    // 16385 f32 (gate 8192 | field 8192 | mean 1)

  // ws: [0, 512K) W1eff bf16, [512K, +32K) delta f32. (Split-K partials gone.)
  char* ws = (char*)d_ws;
  short* W1eff = (short*)ws;
  float* delta = (float*)(ws + (size_t)64 * D_MODEL * 2);

  fold_w1<<<64, 256, 0, stream>>>(W1, Wf, W1eff);
  gemm_fused<<<512, 512, 0, stream>>>(hidden, W1eff, b1, W2, b2, delta);
  ema_out<<<1, 256, 0, stream>>>(delta, lam, out);
}

// Round 2
// 237.181 us; speedup vs baseline: 1.0456x; 1.0456x over previous
//
#include <hip/hip_runtime.h>
#include <hip/hip_bf16.h>

#define D_MODEL 4096
#define NTOK    8192   // B*S = 4*2048
#define SEQ     2048

typedef short bf16x8 __attribute__((ext_vector_type(8)));  // 8 bf16 in 4 VGPRs
typedef float f32x4  __attribute__((ext_vector_type(4)));

__device__ __forceinline__ short f2bf(float x) {
  __hip_bfloat16 h = __float2bfloat16(x);
  return *reinterpret_cast<short*>(&h);
}
__device__ __forceinline__ float bfs2f(unsigned short u) {
  unsigned int x = ((unsigned int)u) << 16;
  float f;
  __builtin_memcpy(&f, &x, 4);
  return f;
}
__device__ __forceinline__ float bf2f(const void* p, size_t i) {
  return bfs2f(((const unsigned short*)p)[i]);
}

// ---------------------------------------------------------------------------
// Wave-level dtype sniff (confirmed: hidden=bf16, weights=f32; kept for
// robustness). Returns 1 -> bf16[], 0 -> float[]. Wave-uniform result.
// ---------------------------------------------------------------------------
__device__ __forceinline__ int sniff_wave(const unsigned short* p, int n) {
  int lane = threadIdx.x & 63;
  int S = n / 2 < 64 ? n / 2 : 64;
  bool act = lane < S;
  unsigned short ve = 0, vo = 0;
  if (act) { ve = p[2 * lane]; vo = p[2 * lane + 1]; }
  int ee = (ve >> 7) & 0xFF, eo = (vo >> 7) & 0xFF;
  bool ve_band   = (ve == 0) || (ve == 0x8000) || (ee >= 96 && ee <= 141);
  bool vo_bandnz = (vo != 0) && (vo != 0x8000) && (eo >= 96 && eo <= 141);
  int zp = __popcll(__ballot(act && ve == 0 && vo == 0));
  int ob = __popcll(__ballot(act && ve == 0 && vo_bandnz));
  int eb = __popcll(__ballot(act && ve_band));
  if (zp == S) return 1;
  if (4 * ob >= 3 * S) return 0;   // f32 storage of bf16-rounded values
  if (4 * eb >= 3 * S) return 1;   // true bf16
  return 0;                        // raw f32
}

__device__ __forceinline__ float decode_lam(const void* lamp) {
  unsigned short l0 = *(const unsigned short*)lamp;
  int le = (l0 >> 7) & 0xFF;
  if (l0 != 0 && l0 != 0x8000 && le >= 96 && le <= 141)
    return bfs2f(l0);
  return *(const float*)lamp;
}
__device__ __forceinline__ float decode_b2(const void* p) {
  unsigned short c0 = *(const unsigned short*)p;
  int ce = (c0 >> 7) & 0xFF;
  if (c0 == 0) return 0.0f;
  if (c0 != 0x8000 && ce >= 96 && ce <= 141)
    return bfs2f(c0);
  return *(const float*)p;
}

// ---------------------------------------------------------------------------
// Kernel 1: fold W_fiber into W1 -> W1_eff[64][4096] bf16 (vectorized).
// ---------------------------------------------------------------------------
__global__ __launch_bounds__(256) void fold_w1(const void* __restrict__ W1v,
                                               const void* __restrict__ Wfv,
                                               short* __restrict__ W1eff) {
  int n = blockIdx.x;  // 0..63
  int fw1 = sniff_wave((const unsigned short*)W1v, 64 * 4112);
  int fwf = sniff_wave((const unsigned short*)Wfv, 16 * D_MODEL);
  __shared__ float w1b[16];
  if (threadIdx.x < 16) {
    size_t idx = (size_t)n * 4112 + 4096 + threadIdx.x;
    w1b[threadIdx.x] = fw1 ? bf2f(W1v, idx) : ((const float*)W1v)[idx];
  }
  __syncthreads();
  for (int it = 0; it < 4; ++it) {
    int k0 = it * 1024 + threadIdx.x * 4;
    size_t idx = (size_t)n * 4112 + k0;
    float v0, v1, v2, v3;
    if (fw1) {
      ushort4 u = *(const ushort4*)((const unsigned short*)W1v + idx);
      v0 = bfs2f(u.x); v1 = bfs2f(u.y); v2 = bfs2f(u.z); v3 = bfs2f(u.w);
    } else {
      float4 f = *(const float4*)((const float*)W1v + idx);
      v0 = f.x; v1 = f.y; v2 = f.z; v3 = f.w;
    }
#pragma unroll
    for (int f = 0; f < 16; ++f) {
      size_t wi = (size_t)f * D_MODEL + k0;
      float w0, w1_, w2_, w3_;
      if (fwf) {
        ushort4 u = *(const ushort4*)((const unsigned short*)Wfv + wi);
        w0 = bfs2f(u.x); w1_ = bfs2f(u.y); w2_ = bfs2f(u.z); w3_ = bfs2f(u.w);
      } else {
        float4 fv = *(const float4*)((const float*)Wfv + wi);
        w0 = fv.x; w1_ = fv.y; w2_ = fv.z; w3_ = fv.w;
      }
      float s = w1b[f];
      v0 += s * w0; v1 += s * w1_; v2 += s * w2_; v3 += s * w3_;
    }
    ushort4 o;
    o.x = (unsigned short)f2bf(v0); o.y = (unsigned short)f2bf(v1);
    o.z = (unsigned short)f2bf(v2); o.w = (unsigned short)f2bf(v3);
    *(ushort4*)(W1eff + (size_t)n * D_MODEL + k0) = o;
  }
}

// ---------------------------------------------------------------------------
// Kernel 2: barrier-free streaming GEMM + fused epilogue.
// Grid 512 blocks x 512 thr (8 waves), block t owns tokens [t*16, +16).
// Wave w = K-eighth: k in [w*512, w*512+512), 16 K-slices of 32.
// NO LDS for B: W1eff (512 KB) is read-only and L2-resident per XCD after
// first touch; B fragments are 16B-contiguous per lane -> direct
// global_load_dwordx4, exactly the shape ds_read_b128 gave. This removes
// ALL main-loop barriers (round-1 kernel was latency-serialized: 64 VGPRs
// meant the compiler sank the A prefetch to the MFMA use points).
// Depth-2 register ring on (A, B0..B3) = 40 VGPRs of in-flight state ->
// 16 waves/CU x ~10KB outstanding = 160 KB/CU in flight (need ~22 KB for
// 6.3 TB/s). K-eighth partials reduced via LDS, then bias + exact GELU +
// dot(W2) + softplus in-block -> delta[16] written directly.
// MFMA 16x16x32 bf16: A[m=lane&15][k=8*(lane>>4)+j]; C: col=lane&15,
// row=(lane>>4)*4+reg (m89/m91-verified; identical mapping to the round-0/1
// kernels which passed with absmax 0.0039).
// ---------------------------------------------------------------------------
__global__ __launch_bounds__(512, 4) void gemm_stream(const void* __restrict__ hid,
                                                      const short* __restrict__ B_,
                                                      const void* __restrict__ b1,
                                                      const void* __restrict__ w2,
                                                      const void* __restrict__ b2,
                                                      float* __restrict__ delta) {
  int t = blockIdx.x;                 // token tile 0..511
  int w = threadIdx.x >> 6, lane = threadIdx.x & 63;
  int m = lane & 15, kg = lane >> 4;

  __shared__ float red[8][16][68];    // 34.8 KB: per-K-eighth partials (pitch 68)

  int fhid = sniff_wave((const unsigned short*)hid, NTOK * D_MODEL);

  f32x4 acc0 = {0.f, 0.f, 0.f, 0.f};
  f32x4 acc1 = acc0, acc2 = acc0, acc3 = acc0;

  size_t abase = (size_t)(t * 16 + m) * D_MODEL + w * 512 + kg * 8;
  const short* Bp = B_ + (size_t)m * D_MODEL + w * 512 + kg * 8;  // + nc*16*D_MODEL

  if (fhid) {  // hidden bf16 (confirmed path)
    const short* Ap = (const short*)hid + abase;
    bf16x8 ar[2], br[2][4];
#pragma unroll
    for (int p = 0; p < 2; ++p) {
      ar[p] = *(const bf16x8*)(Ap + p * 32);
#pragma unroll
      for (int nc = 0; nc < 4; ++nc)
        br[p][nc] = *(const bf16x8*)(Bp + (size_t)nc * 16 * D_MODEL + p * 32);
    }
#pragma unroll
    for (int s = 0; s < 16; ++s) {
      int cur = s & 1;
      bf16x8 a  = ar[cur];
      bf16x8 f0 = br[cur][0], f1 = br[cur][1], f2 = br[cur][2], f3 = br[cur][3];
      if (s + 2 < 16) {
        ar[cur] = *(const bf16x8*)(Ap + (s + 2) * 32);
#pragma unroll
        for (int nc = 0; nc < 4; ++nc)
          br[cur][nc] = *(const bf16x8*)(Bp + (size_t)nc * 16 * D_MODEL + (s + 2) * 32);
      }
      acc0 = __builtin_amdgcn_mfma_f32_16x16x32_bf16(a, f0, acc0, 0, 0, 0);
      acc1 = __builtin_amdgcn_mfma_f32_16x16x32_bf16(a, f1, acc1, 0, 0, 0);
      acc2 = __builtin_amdgcn_mfma_f32_16x16x32_bf16(a, f2, acc2, 0, 0, 0);
      acc3 = __builtin_amdgcn_mfma_f32_16x16x32_bf16(a, f3, acc3, 0, 0, 0);
    }
  } else {     // hidden f32 fallback (correctness path, demand loads)
    const float* Ap = (const float*)hid + abase;
    for (int s = 0; s < 16; ++s) {
      float4 lo = *(const float4*)(Ap + s * 32);
      float4 hi = *(const float4*)(Ap + s * 32 + 4);
      bf16x8 a;
      a[0] = f2bf(lo.x); a[1] = f2bf(lo.y); a[2] = f2bf(lo.z); a[3] = f2bf(lo.w);
      a[4] = f2bf(hi.x); a[5] = f2bf(hi.y); a[6] = f2bf(hi.z); a[7] = f2bf(hi.w);
#pragma unroll
      for (int nc = 0; nc < 4; ++nc) {
        bf16x8 bb = *(const bf16x8*)(Bp + (size_t)nc * 16 * D_MODEL + s * 32);
        if (nc == 0) acc0 = __builtin_amdgcn_mfma_f32_16x16x32_bf16(a, bb, acc0, 0, 0, 0);
        if (nc == 1) acc1 = __builtin_amdgcn_mfma_f32_16x16x32_bf16(a, bb, acc1, 0, 0, 0);
        if (nc == 2) acc2 = __builtin_amdgcn_mfma_f32_16x16x32_bf16(a, bb, acc2, 0, 0, 0);
        if (nc == 3) acc3 = __builtin_amdgcn_mfma_f32_16x16x32_bf16(a, bb, acc3, 0, 0, 0);
      }
    }
  }

  // ---- write per-K-eighth partials: red[w][tok][col] ----
#pragma unroll
  for (int r = 0; r < 4; ++r) {
    int tok = kg * 4 + r;
    red[w][tok][m +  0] = acc0[r];
    red[w][tok][m + 16] = acc1[r];
    red[w][tok][m + 32] = acc2[r];
    red[w][tok][m + 48] = acc3[r];
  }
  __syncthreads();

  // ---- epilogue on waves 0..3: reduce 8 eighths, +b1, GELU, *W2, softplus ----
  if (threadIdx.x < 256) {
    int tok = threadIdx.x >> 4;      // 0..15
    int cid = threadIdx.x & 15;
    int fb1 = sniff_wave((const unsigned short*)b1, 64);
    int fw2 = sniff_wave((const unsigned short*)w2, 64);
    float y = 0.f;
#pragma unroll
    for (int j = 0; j < 4; ++j) {
      int col = cid + 16 * j;
      float s = 0.f;
#pragma unroll
      for (int q = 0; q < 8; ++q) s += red[q][tok][col];
      s += fb1 ? bf2f(b1, col) : ((const float*)b1)[col];
      float g = 0.5f * s * (1.0f + erff(s * 0.70710678118654752f));  // exact GELU
      y += g * (fw2 ? bf2f(w2, col) : ((const float*)w2)[col]);
    }
#pragma unroll
    for (int off = 1; off <= 8; off <<= 1) y += __shfl_xor(y, off, 64);
    if (cid == 0) {
      float x = y + decode_b2(b2);
      float d = (x > 20.0f) ? x : log1pf(expf(x));  // softplus
      delta[t * 16 + tok] = d;
    }
  }
}

// ---------------------------------------------------------------------------
// Kernel 3: causal EMA, gate, field, mean. OUTPUT IS FLOAT32 (mixed tuple
// (bf16,bf16,f32) concatenated by harness -> numpy-promoted f32).
// ---------------------------------------------------------------------------
__global__ __launch_bounds__(256) void ema_out(const float* __restrict__ delta,
                                               const void* __restrict__ lamp,
                                               float* __restrict__ out) {
  int b    = threadIdx.x >> 6;   // batch 0..3
  int lane = threadIdx.x & 63;
  const float alpha = 0.9f;
  float d[32];
  const float* dp = delta + b * SEQ + lane * 32;
  float beta = 0.f, lsum = 0.f;
#pragma unroll
  for (int i = 0; i < 32; ++i) {
    d[i] = dp[i];
    lsum += d[i];
    beta = alpha * beta + 0.1f * d[i];
  }
  float accA = 0.03433683820292512f;  // 0.9^32
  float accB = beta;
  for (int off = 1; off < 64; off <<= 1) {
    float uA = __shfl_up(accA, off, 64);
    float uB = __shfl_up(accB, off, 64);
    if (lane >= off) {
      accB = accB + accA * uB;  // cur o prev
      accA = accA * uA;
    }
  }
  float prev = __shfl_up(accB, 1, 64);
  float h = (lane == 0) ? 0.f : prev;  // carry-in state for this chunk
  float lam = decode_lam(lamp);
#pragma unroll
  for (int i = 0; i < 32; ++i) {
    h = alpha * h + 0.1f * d[i];
    float gate = 1.0f / (1.0f + expf(lam * h));  // sigmoid(-lam*h)
    out[b * SEQ + lane * 32 + i]        = gate;
    out[NTOK + b * SEQ + lane * 32 + i] = h;
  }
#pragma unroll
  for (int off = 32; off >= 1; off >>= 1) lsum += __shfl_xor(lsum, off, 64);
  __shared__ float bs[4];
  if (lane == 0) bs[b] = lsum;
  __syncthreads();
  if (threadIdx.x == 0)
    out[2 * NTOK] = (bs[0] + bs[1] + bs[2] + bs[3]) * (1.0f / 8192.0f);
}

// ---------------------------------------------------------------------------
extern "C" void kernel_launch(void* const* d_in, const int* in_sizes, int n_in,
                              void* d_out, int out_size, void* d_ws, size_t ws_size,
                              hipStream_t stream) {
  const void* hidden = d_in[0];  // [4,2048,4096]
  const void* Wf     = d_in[1];  // [16,4096]
  const void* W1     = d_in[2];  // [64,4112]
  const void* b1     = d_in[3];  // [64]
  const void* W2     = d_in[4];  // [1,64]
  const void* b2     = d_in[5];  // [1]
  const void* lam    = d_in[6];  // [1]
  float* out = (float*)d_out;    // 16385 f32 (gate 8192 | field 8192 | mean 1)

  // ws: [0, 512K) W1eff bf16, [512K, +32K) delta f32.
  char* ws = (char*)d_ws;
  short* W1eff = (short*)ws;
  float* delta = (float*)(ws + (size_t)64 * D_MODEL * 2);

  fold_w1<<<64, 256, 0, stream>>>(W1, Wf, W1eff);
  gemm_stream<<<512, 512, 0, stream>>>(hidden, W1eff, b1, W2, b2, delta);
  ema_out<<<1, 256, 0, stream>>>(delta, lam, out);
}

// Round 3
// 233.535 us; speedup vs baseline: 1.0619x; 1.0156x over previous
//
#include <hip/hip_runtime.h>
#include <hip/hip_bf16.h>

#define D_MODEL 4096
#define NTOK    8192   // B*S = 4*2048
#define SEQ     2048

typedef short bf16x8 __attribute__((ext_vector_type(8)));  // 8 bf16 in 4 VGPRs
typedef float f32x4  __attribute__((ext_vector_type(4)));

__device__ __forceinline__ short f2bf(float x) {
  __hip_bfloat16 h = __float2bfloat16(x);
  return *reinterpret_cast<short*>(&h);
}
__device__ __forceinline__ float bfs2f(unsigned short u) {
  unsigned int x = ((unsigned int)u) << 16;
  float f;
  __builtin_memcpy(&f, &x, 4);
  return f;
}
__device__ __forceinline__ float bf2f(const void* p, size_t i) {
  return bfs2f(((const unsigned short*)p)[i]);
}

// Async global->LDS, 16B per lane. LDS dest must be the WAVE-UNIFORM base
// (HW adds lane*16); global src is per-lane (guide m104/m173).
__device__ __forceinline__ void gload_lds16(const void* g, void* l) {
  __builtin_amdgcn_global_load_lds(
      (__attribute__((address_space(1))) void*)(g),
      (__attribute__((address_space(3))) void*)(l), 16, 0, 0);
}

// ---------------------------------------------------------------------------
// Wave-level dtype sniff (confirmed: hidden=bf16, weights=f32; kept for
// robustness). Returns 1 -> bf16[], 0 -> float[]. Wave-uniform result.
// ---------------------------------------------------------------------------
__device__ __forceinline__ int sniff_wave(const unsigned short* p, int n) {
  int lane = threadIdx.x & 63;
  int S = n / 2 < 64 ? n / 2 : 64;
  bool act = lane < S;
  unsigned short ve = 0, vo = 0;
  if (act) { ve = p[2 * lane]; vo = p[2 * lane + 1]; }
  int ee = (ve >> 7) & 0xFF, eo = (vo >> 7) & 0xFF;
  bool ve_band   = (ve == 0) || (ve == 0x8000) || (ee >= 96 && ee <= 141);
  bool vo_bandnz = (vo != 0) && (vo != 0x8000) && (eo >= 96 && eo <= 141);
  int zp = __popcll(__ballot(act && ve == 0 && vo == 0));
  int ob = __popcll(__ballot(act && ve == 0 && vo_bandnz));
  int eb = __popcll(__ballot(act && ve_band));
  if (zp == S) return 1;
  if (4 * ob >= 3 * S) return 0;   // f32 storage of bf16-rounded values
  if (4 * eb >= 3 * S) return 1;   // true bf16
  return 0;                        // raw f32
}

__device__ __forceinline__ float decode_lam(const void* lamp) {
  unsigned short l0 = *(const unsigned short*)lamp;
  int le = (l0 >> 7) & 0xFF;
  if (l0 != 0 && l0 != 0x8000 && le >= 96 && le <= 141)
    return bfs2f(l0);
  return *(const float*)lamp;
}
__device__ __forceinline__ float decode_b2(const void* p) {
  unsigned short c0 = *(const unsigned short*)p;
  int ce = (c0 >> 7) & 0xFF;
  if (c0 == 0) return 0.0f;
  if (c0 != 0x8000 && ce >= 96 && ce <= 141)
    return bfs2f(c0);
  return *(const float*)p;
}

// ---------------------------------------------------------------------------
// Kernel 1: fold W_fiber into W1 -> W1_eff[64][4096] bf16 (vectorized).
// ---------------------------------------------------------------------------
__global__ __launch_bounds__(256) void fold_w1(const void* __restrict__ W1v,
                                               const void* __restrict__ Wfv,
                                               short* __restrict__ W1eff) {
  int n = blockIdx.x;  // 0..63
  int fw1 = sniff_wave((const unsigned short*)W1v, 64 * 4112);
  int fwf = sniff_wave((const unsigned short*)Wfv, 16 * D_MODEL);
  __shared__ float w1b[16];
  if (threadIdx.x < 16) {
    size_t idx = (size_t)n * 4112 + 4096 + threadIdx.x;
    w1b[threadIdx.x] = fw1 ? bf2f(W1v, idx) : ((const float*)W1v)[idx];
  }
  __syncthreads();
  for (int it = 0; it < 4; ++it) {
    int k0 = it * 1024 + threadIdx.x * 4;
    size_t idx = (size_t)n * 4112 + k0;
    float v0, v1, v2, v3;
    if (fw1) {
      ushort4 u = *(const ushort4*)((const unsigned short*)W1v + idx);
      v0 = bfs2f(u.x); v1 = bfs2f(u.y); v2 = bfs2f(u.z); v3 = bfs2f(u.w);
    } else {
      float4 f = *(const float4*)((const float*)W1v + idx);
      v0 = f.x; v1 = f.y; v2 = f.z; v3 = f.w;
    }
#pragma unroll
    for (int f = 0; f < 16; ++f) {
      size_t wi = (size_t)f * D_MODEL + k0;
      float w0, w1_, w2_, w3_;
      if (fwf) {
        ushort4 u = *(const ushort4*)((const unsigned short*)Wfv + wi);
        w0 = bfs2f(u.x); w1_ = bfs2f(u.y); w2_ = bfs2f(u.z); w3_ = bfs2f(u.w);
      } else {
        float4 fv = *(const float4*)((const float*)Wfv + wi);
        w0 = fv.x; w1_ = fv.y; w2_ = fv.z; w3_ = fv.w;
      }
      float s = w1b[f];
      v0 += s * w0; v1 += s * w1_; v2 += s * w2_; v3 += s * w3_;
    }
    ushort4 o;
    o.x = (unsigned short)f2bf(v0); o.y = (unsigned short)f2bf(v1);
    o.z = (unsigned short)f2bf(v2); o.w = (unsigned short)f2bf(v3);
    *(ushort4*)(W1eff + (size_t)n * D_MODEL + k0) = o;
  }
}

// ---------------------------------------------------------------------------
// Kernel 2: GEMM with global_load_lds A-staging (m97 machinery) + fused
// epilogue. Grid 512 x 512 thr (8 waves), 2 blocks/CU (LDS 64 KB).
// Block t owns tokens [t*16,+16) over full K=4096 in 4 chunks of 1024.
// A-chunk = 16 rows x 2048 B = 32 KB, double-buffered. Staging: each wave
// issues 4x global_load_lds(16B) covering 2 rows; LDS dest is LINEAR
// (wave base + lane*16, HW requirement); the T2 bank swizzle
// (byte ^= (row&7)<<4) is applied by INVERSE-swizzling the per-lane GLOBAL
// source (m173 pattern) -> every instr is one row-half = 8x128B coalesced
// segments. ds_read_b128 fragments use the same XOR -> 8 lanes per 16B slot
// = the b128 floor (conflict-free).
// Chunk loop = T3 minimum 2-phase: {stage(c+1) issue -> compute(c) ->
// barrier(+vmcnt drain)} -- staging flight hidden under 32 MFMA+B-loads.
// Waves split each chunk's K 8 ways (w -> cols [w*128,+128), 4 slices);
// per-wave K-partials reduced via LDS aliased over the dead A-buffers.
// B direct from L2 (512 KB W1eff, resident per XCD), depth-2 reg ring.
// MFMA 16x16x32 bf16: A[m=lane&15][k=8*(lane>>4)+j]; C: col=lane&15,
// row=(lane>>4)*4+reg (m89/m91-verified, unchanged from passing rounds).
// ---------------------------------------------------------------------------
__global__ __launch_bounds__(512, 4) void gemm_lds(const void* __restrict__ hid,
                                                   const short* __restrict__ B_,
                                                   const void* __restrict__ b1,
                                                   const void* __restrict__ w2,
                                                   const void* __restrict__ b2,
                                                   float* __restrict__ delta) {
  int t = blockIdx.x;                 // token tile 0..511
  int w = threadIdx.x >> 6, lane = threadIdx.x & 63;
  int m = lane & 15, kg = lane >> 4;

  __shared__ char smem[65536];        // [2][32KB] A chunk buffers; red aliased

  int fhid = sniff_wave((const unsigned short*)hid, NTOK * D_MODEL);

  f32x4 acc0 = {0.f, 0.f, 0.f, 0.f};
  f32x4 acc1 = acc0, acc2 = acc0, acc3 = acc0;

  const short* Bp = B_ + (size_t)m * D_MODEL + kg * 8;  // + nc*16*D_MODEL + ko

  if (fhid) {  // hidden bf16 (confirmed path)
    // ---- prime B ring (slices g=0,1) BEFORE staging (older vmcnt slot) ----
    bf16x8 br[2][4];
#pragma unroll
    for (int p = 0; p < 2; ++p) {
      int ko = (p >> 2) * 1024 + w * 128 + (p & 3) * 32;
#pragma unroll
      for (int nc = 0; nc < 4; ++nc)
        br[p][nc] = *(const bf16x8*)(Bp + (size_t)nc * 16 * D_MODEL + ko);
    }
    // ---- prologue: stage chunk 0 into buf0 ----
#pragma unroll
    for (int j = 0; j < 4; ++j) {
      int dloc = w * 4096 + j * 1024 + lane * 16;   // linear byte in 32KB chunk
      int row  = dloc >> 11;                        // 0..15
      int cb0  = (dloc & 2047) ^ ((row & 7) << 4);  // inverse swizzle on source
      const char* g = (const char*)hid +
          ((size_t)(t * 16 + row) * D_MODEL) * 2 + cb0;
      gload_lds16(g, smem + (w * 4096 + j * 1024)); // wave-uniform dest base
    }
    __syncthreads();                                // drains vmcnt -> chunk0 ready

#pragma unroll
    for (int c = 0; c < 4; ++c) {
      int buf = c & 1;
      // ---- issue stage of chunk c+1 into other buffer (overlaps compute) ----
      if (c < 3) {
#pragma unroll
        for (int j = 0; j < 4; ++j) {
          int dloc = w * 4096 + j * 1024 + lane * 16;
          int row  = dloc >> 11;
          int cb0  = (dloc & 2047) ^ ((row & 7) << 4);
          const char* g = (const char*)hid +
              ((size_t)(t * 16 + row) * D_MODEL + (size_t)(c + 1) * 1024) * 2 + cb0;
          gload_lds16(g, smem + ((buf ^ 1) * 32768 + w * 4096 + j * 1024));
        }
      }
      // ---- compute chunk c: 4 slices ----
#pragma unroll
      for (int s = 0; s < 4; ++s) {
        int g = c * 4 + s;
        int cb = w * 256 + s * 64 + kg * 16;        // logical col byte in chunk
        bf16x8 a = *(const bf16x8*)(smem + buf * 32768 + m * 2048 +
                                    (cb ^ ((m & 7) << 4)));
        int cur = g & 1;
        bf16x8 f0 = br[cur][0], f1 = br[cur][1], f2 = br[cur][2], f3 = br[cur][3];
        if (g + 2 < 16) {
          int ko = ((g + 2) >> 2) * 1024 + w * 128 + ((g + 2) & 3) * 32;
#pragma unroll
          for (int nc = 0; nc < 4; ++nc)
            br[cur][nc] = *(const bf16x8*)(Bp + (size_t)nc * 16 * D_MODEL + ko);
        }
        acc0 = __builtin_amdgcn_mfma_f32_16x16x32_bf16(a, f0, acc0, 0, 0, 0);
        acc1 = __builtin_amdgcn_mfma_f32_16x16x32_bf16(a, f1, acc1, 0, 0, 0);
        acc2 = __builtin_amdgcn_mfma_f32_16x16x32_bf16(a, f2, acc2, 0, 0, 0);
        acc3 = __builtin_amdgcn_mfma_f32_16x16x32_bf16(a, f3, acc3, 0, 0, 0);
      }
      __syncthreads();   // joins reads of buf + drains stage(c+1) -> ready
    }
  } else {     // hidden f32 fallback (correctness path, demand loads)
    const float* Ap = (const float*)hid + (size_t)(t * 16 + m) * D_MODEL + kg * 8;
    for (int g = 0; g < 16; ++g) {
      int ko = (g >> 2) * 1024 + w * 128 + (g & 3) * 32;
      float4 lo = *(const float4*)(Ap + ko);
      float4 hi = *(const float4*)(Ap + ko + 4);
      bf16x8 a;
      a[0] = f2bf(lo.x); a[1] = f2bf(lo.y); a[2] = f2bf(lo.z); a[3] = f2bf(lo.w);
      a[4] = f2bf(hi.x); a[5] = f2bf(hi.y); a[6] = f2bf(hi.z); a[7] = f2bf(hi.w);
#pragma unroll
      for (int nc = 0; nc < 4; ++nc) {
        bf16x8 bb = *(const bf16x8*)(Bp + (size_t)nc * 16 * D_MODEL + ko);
        if (nc == 0) acc0 = __builtin_amdgcn_mfma_f32_16x16x32_bf16(a, bb, acc0, 0, 0, 0);
        if (nc == 1) acc1 = __builtin_amdgcn_mfma_f32_16x16x32_bf16(a, bb, acc1, 0, 0, 0);
        if (nc == 2) acc2 = __builtin_amdgcn_mfma_f32_16x16x32_bf16(a, bb, acc2, 0, 0, 0);
        if (nc == 3) acc3 = __builtin_amdgcn_mfma_f32_16x16x32_bf16(a, bb, acc3, 0, 0, 0);
      }
    }
    __syncthreads();  // align with bf16 path before red aliasing
  }

  // ---- per-wave K-partials into LDS (aliases dead A buffers; last barrier
  //      above guarantees all A reads complete) ----
  float* redf = (float*)smem;          // [8][16][68] = 34.8 KB
#pragma unroll
  for (int r = 0; r < 4; ++r) {
    int tok = kg * 4 + r;
    float* rp = redf + (size_t)(w * 16 + tok) * 68;
    rp[m +  0] = acc0[r];
    rp[m + 16] = acc1[r];
    rp[m + 32] = acc2[r];
    rp[m + 48] = acc3[r];
  }
  __syncthreads();

  // ---- epilogue: reduce 8 K-parts, +b1, exact GELU, *W2, softplus ----
  if (threadIdx.x < 256) {
    int tok = threadIdx.x >> 4;      // 0..15
    int cid = threadIdx.x & 15;
    int fb1 = sniff_wave((const unsigned short*)b1, 64);
    int fw2 = sniff_wave((const unsigned short*)w2, 64);
    float y = 0.f;
#pragma unroll
    for (int j = 0; j < 4; ++j) {
      int col = cid + 16 * j;
      float s = 0.f;
#pragma unroll
      for (int q = 0; q < 8; ++q) s += redf[(size_t)(q * 16 + tok) * 68 + col];
      s += fb1 ? bf2f(b1, col) : ((const float*)b1)[col];
      float g = 0.5f * s * (1.0f + erff(s * 0.70710678118654752f));  // exact GELU
      y += g * (fw2 ? bf2f(w2, col) : ((const float*)w2)[col]);
    }
#pragma unroll
    for (int off = 1; off <= 8; off <<= 1) y += __shfl_xor(y, off, 64);
    if (cid == 0) {
      float x = y + decode_b2(b2);
      float d = (x > 20.0f) ? x : log1pf(expf(x));  // softplus
      delta[t * 16 + tok] = d;
    }
  }
}

// ---------------------------------------------------------------------------
// Kernel 3: causal EMA, gate, field, mean. OUTPUT IS FLOAT32 (mixed tuple
// (bf16,bf16,f32) concatenated by harness -> numpy-promoted f32).
// ---------------------------------------------------------------------------
__global__ __launch_bounds__(256) void ema_out(const float* __restrict__ delta,
                                               const void* __restrict__ lamp,
                                               float* __restrict__ out) {
  int b    = threadIdx.x >> 6;   // batch 0..3
  int lane = threadIdx.x & 63;
  const float alpha = 0.9f;
  float d[32];
  const float* dp = delta + b * SEQ + lane * 32;
  float beta = 0.f, lsum = 0.f;
#pragma unroll
  for (int i = 0; i < 32; ++i) {
    d[i] = dp[i];
    lsum += d[i];
    beta = alpha * beta + 0.1f * d[i];
  }
  float accA = 0.03433683820292512f;  // 0.9^32
  float accB = beta;
  for (int off = 1; off < 64; off <<= 1) {
    float uA = __shfl_up(accA, off, 64);
    float uB = __shfl_up(accB, off, 64);
    if (lane >= off) {
      accB = accB + accA * uB;  // cur o prev
      accA = accA * uA;
    }
  }
  float prev = __shfl_up(accB, 1, 64);
  float h = (lane == 0) ? 0.f : prev;  // carry-in state for this chunk
  float lam = decode_lam(lamp);
#pragma unroll
  for (int i = 0; i < 32; ++i) {
    h = alpha * h + 0.1f * d[i];
    float gate = 1.0f / (1.0f + expf(lam * h));  // sigmoid(-lam*h)
    out[b * SEQ + lane * 32 + i]        = gate;
    out[NTOK + b * SEQ + lane * 32 + i] = h;
  }
#pragma unroll
  for (int off = 32; off >= 1; off >>= 1) lsum += __shfl_xor(lsum, off, 64);
  __shared__ float bs[4];
  if (lane == 0) bs[b] = lsum;
  __syncthreads();
  if (threadIdx.x == 0)
    out[2 * NTOK] = (bs[0] + bs[1] + bs[2] + bs[3]) * (1.0f / 8192.0f);
}

// ---------------------------------------------------------------------------
extern "C" void kernel_launch(void* const* d_in, const int* in_sizes, int n_in,
                              void* d_out, int out_size, void* d_ws, size_t ws_size,
                              hipStream_t stream) {
  const void* hidden = d_in[0];  // [4,2048,4096]
  const void* Wf     = d_in[1];  // [16,4096]
  const void* W1     = d_in[2];  // [64,4112]
  const void* b1     = d_in[3];  // [64]
  const void* W2     = d_in[4];  // [1,64]
  const void* b2     = d_in[5];  // [1]
  const void* lam    = d_in[6];  // [1]
  float* out = (float*)d_out;    // 16385 f32 (gate 8192 | field 8192 | mean 1)

  // ws: [0, 512K) W1eff bf16, [512K, +32K) delta f32.
  char* ws = (char*)d_ws;
  short* W1eff = (short*)ws;
  float* delta = (float*)(ws + (size_t)64 * D_MODEL * 2);

  fold_w1<<<64, 256, 0, stream>>>(W1, Wf, W1eff);
  gemm_lds<<<512, 512, 0, stream>>>(hidden, W1eff, b1, W2, b2, delta);
  ema_out<<<1, 256, 0, stream>>>(delta, lam, out);
}

// Round 4
// 230.791 us; speedup vs baseline: 1.0745x; 1.0119x over previous
//
#include <hip/hip_runtime.h>
#include <hip/hip_bf16.h>

#define D_MODEL 4096
#define NTOK    8192   // B*S = 4*2048
#define SEQ     2048

typedef short bf16x8 __attribute__((ext_vector_type(8)));  // 8 bf16 in 4 VGPRs
typedef float f32x4  __attribute__((ext_vector_type(4)));

__device__ __forceinline__ short f2bf(float x) {
  __hip_bfloat16 h = __float2bfloat16(x);
  return *reinterpret_cast<short*>(&h);
}
__device__ __forceinline__ float bfs2f(unsigned short u) {
  unsigned int x = ((unsigned int)u) << 16;
  float f;
  __builtin_memcpy(&f, &x, 4);
  return f;
}
__device__ __forceinline__ float bf2f(const void* p, size_t i) {
  return bfs2f(((const unsigned short*)p)[i]);
}

// Async global->LDS, 16B per lane. LDS dest is the WAVE-UNIFORM base
// (HW adds lane*16); global src is per-lane (guide m104/m173).
__device__ __forceinline__ void gload_lds16(const void* g, void* l) {
  __builtin_amdgcn_global_load_lds(
      (__attribute__((address_space(1))) void*)(g),
      (__attribute__((address_space(3))) void*)(l), 16, 0, 0);
}

// ---------------------------------------------------------------------------
// Wave-level dtype sniff (confirmed: hidden=bf16, weights=f32; kept for
// robustness). Returns 1 -> bf16[], 0 -> float[]. Block-uniform result.
// ---------------------------------------------------------------------------
__device__ __forceinline__ int sniff_wave(const unsigned short* p, int n) {
  int lane = threadIdx.x & 63;
  int S = n / 2 < 64 ? n / 2 : 64;
  bool act = lane < S;
  unsigned short ve = 0, vo = 0;
  if (act) { ve = p[2 * lane]; vo = p[2 * lane + 1]; }
  int ee = (ve >> 7) & 0xFF, eo = (vo >> 7) & 0xFF;
  bool ve_band   = (ve == 0) || (ve == 0x8000) || (ee >= 96 && ee <= 141);
  bool vo_bandnz = (vo != 0) && (vo != 0x8000) && (eo >= 96 && eo <= 141);
  int zp = __popcll(__ballot(act && ve == 0 && vo == 0));
  int ob = __popcll(__ballot(act && ve == 0 && vo_bandnz));
  int eb = __popcll(__ballot(act && ve_band));
  if (zp == S) return 1;
  if (4 * ob >= 3 * S) return 0;   // f32 storage of bf16-rounded values
  if (4 * eb >= 3 * S) return 1;   // true bf16
  return 0;                        // raw f32
}

__device__ __forceinline__ float decode_lam(const void* lamp) {
  unsigned short l0 = *(const unsigned short*)lamp;
  int le = (l0 >> 7) & 0xFF;
  if (l0 != 0 && l0 != 0x8000 && le >= 96 && le <= 141)
    return bfs2f(l0);
  return *(const float*)lamp;
}
__device__ __forceinline__ float decode_b2(const void* p) {
  unsigned short c0 = *(const unsigned short*)p;
  int ce = (c0 >> 7) & 0xFF;
  if (c0 == 0) return 0.0f;
  if (c0 != 0x8000 && ce >= 96 && ce <= 141)
    return bfs2f(c0);
  return *(const float*)p;
}

// ---------------------------------------------------------------------------
// Kernel 1: fold W_fiber into W1 -> W1_eff[64][4096] bf16 (vectorized).
// ---------------------------------------------------------------------------
__global__ __launch_bounds__(256) void fold_w1(const void* __restrict__ W1v,
                                               const void* __restrict__ Wfv,
                                               short* __restrict__ W1eff) {
  int n = blockIdx.x;  // 0..63
  int fw1 = sniff_wave((const unsigned short*)W1v, 64 * 4112);
  int fwf = sniff_wave((const unsigned short*)Wfv, 16 * D_MODEL);
  __shared__ float w1b[16];
  if (threadIdx.x < 16) {
    size_t idx = (size_t)n * 4112 + 4096 + threadIdx.x;
    w1b[threadIdx.x] = fw1 ? bf2f(W1v, idx) : ((const float*)W1v)[idx];
  }
  __syncthreads();
  for (int it = 0; it < 4; ++it) {
    int k0 = it * 1024 + threadIdx.x * 4;
    size_t idx = (size_t)n * 4112 + k0;
    float v0, v1, v2, v3;
    if (fw1) {
      ushort4 u = *(const ushort4*)((const unsigned short*)W1v + idx);
      v0 = bfs2f(u.x); v1 = bfs2f(u.y); v2 = bfs2f(u.z); v3 = bfs2f(u.w);
    } else {
      float4 f = *(const float4*)((const float*)W1v + idx);
      v0 = f.x; v1 = f.y; v2 = f.z; v3 = f.w;
    }
#pragma unroll
    for (int f = 0; f < 16; ++f) {
      size_t wi = (size_t)f * D_MODEL + k0;
      float w0, w1_, w2_, w3_;
      if (fwf) {
        ushort4 u = *(const ushort4*)((const unsigned short*)Wfv + wi);
        w0 = bfs2f(u.x); w1_ = bfs2f(u.y); w2_ = bfs2f(u.z); w3_ = bfs2f(u.w);
      } else {
        float4 fv = *(const float4*)((const float*)Wfv + wi);
        w0 = fv.x; w1_ = fv.y; w2_ = fv.z; w3_ = fv.w;
      }
      float s = w1b[f];
      v0 += s * w0; v1 += s * w1_; v2 += s * w2_; v3 += s * w3_;
    }
    ushort4 o;
    o.x = (unsigned short)f2bf(v0); o.y = (unsigned short)f2bf(v1);
    o.z = (unsigned short)f2bf(v2); o.w = (unsigned short)f2bf(v3);
    *(ushort4*)(W1eff + (size_t)n * D_MODEL + k0) = o;
  }
}

// ---------------------------------------------------------------------------
// Kernel 2: split-K GEMM partials, ONE memory phase per wave.
// Grid 512 = 8 K-chunks x 64 M-tiles, blockIdx = c*64 + t (XCD = t%8 for all
// chunks of tile t -> A rows fetched once per XCD-L2; partials L2-local for
// delta_ep's matching swizzle). Block 512 thr (8 waves), wave w = rows
// [t*128 + w*16, +16) over K-chunk [c*512, +512).
// Phase 1 (all before ONE barrier, so the compiler CANNOT sink anything —
// rounds 0-3 all lost to sunk prefetch rings, VGPR 60-64 proved it):
//   - 8x global_load_lds(16B): B-chunk 64x512 bf16 -> 64 KB LDS, row-major
//     rows n at byte n*1024, 16B-unit u stored at slot u^(n&7) (XOR
//     involution applied on the SOURCE address, R3-proven pattern).
//   - 16x global_load_dwordx4: the wave's ENTIRE A-strip (16 KB) into
//     areg[16]. 16 waves/CU x 16KB = 256 KB/CU in flight at the barrier.
// Phase 2: pure LDS+MFMA, 16 k-steps, zero global waits. Partial stores
// fire-and-forget.
// MFMA 16x16x32 bf16: A[m=lane&15][k=8*(lane>>4)+j]; C: col=lane&15,
// row=(lane>>4)*4+reg (m89/m91-verified, carried from passing rounds).
// ---------------------------------------------------------------------------
__global__ __launch_bounds__(512, 4) void gemm_part(const void* __restrict__ hid,
                                                    const short* __restrict__ B_,
                                                    float* __restrict__ part) {
  int c = blockIdx.x >> 6;          // K-chunk 0..7
  int t = blockIdx.x & 63;          // M-tile 0..63 (128 rows each)
  int w    = threadIdx.x >> 6;      // wave 0..7 = row strip
  int lane = threadIdx.x & 63;
  int m = lane & 15, kg = lane >> 4;

  __shared__ short Bs[64 * 512];    // 64 KB: row-major, unit-XOR swizzled

  int fhid = sniff_wave((const unsigned short*)hid, NTOK * D_MODEL);

  // ---- stage B chunk: 8 instrs/wave, each one full row (8x128B coalesced,
  //      lanes permuted by the XOR involution on the source) ----
#pragma unroll
  for (int i = 0; i < 8; ++i) {
    int n = w * 8 + i;              // 0..63, wave-uniform
    const char* src = (const char*)(B_ + (size_t)n * D_MODEL + c * 512) +
                      ((lane ^ (n & 7)) * 16);
    gload_lds16(src, (char*)Bs + n * 1024);
  }

  f32x4 acc0 = {0.f, 0.f, 0.f, 0.f};
  f32x4 acc1 = acc0, acc2 = acc0, acc3 = acc0;
  size_t abase = (size_t)(t * 128 + w * 16 + m) * D_MODEL + c * 512 + kg * 8;

  if (fhid) {  // hidden bf16 (confirmed path)
    const short* Ap = (const short*)hid + abase;
    bf16x8 areg[16];                // 64 VGPRs, all 16 loads independent
#pragma unroll
    for (int i = 0; i < 16; ++i) areg[i] = *(const bf16x8*)(Ap + i * 32);
    __syncthreads();                // single drain: A regs + B LDS both ready
#pragma unroll
    for (int s = 0; s < 16; ++s) {
      int u  = s * 4 + kg;          // logical 16B-unit within chunk
      int sw = (u ^ (m & 7)) * 16;  // physical slot byte ((m+16nc)&7 == m&7)
      bf16x8 b0 = *(const bf16x8*)((const char*)Bs + (m +  0) * 1024 + sw);
      bf16x8 b1 = *(const bf16x8*)((const char*)Bs + (m + 16) * 1024 + sw);
      bf16x8 b2 = *(const bf16x8*)((const char*)Bs + (m + 32) * 1024 + sw);
      bf16x8 b3 = *(const bf16x8*)((const char*)Bs + (m + 48) * 1024 + sw);
      acc0 = __builtin_amdgcn_mfma_f32_16x16x32_bf16(areg[s], b0, acc0, 0, 0, 0);
      acc1 = __builtin_amdgcn_mfma_f32_16x16x32_bf16(areg[s], b1, acc1, 0, 0, 0);
      acc2 = __builtin_amdgcn_mfma_f32_16x16x32_bf16(areg[s], b2, acc2, 0, 0, 0);
      acc3 = __builtin_amdgcn_mfma_f32_16x16x32_bf16(areg[s], b3, acc3, 0, 0, 0);
    }
  } else {     // hidden f32 fallback (correctness path, demand loads)
    const float* Ap = (const float*)hid + abase;
    __syncthreads();                // B LDS ready
    for (int s = 0; s < 16; ++s) {
      float4 lo = *(const float4*)(Ap + s * 32);
      float4 hi = *(const float4*)(Ap + s * 32 + 4);
      bf16x8 a;
      a[0] = f2bf(lo.x); a[1] = f2bf(lo.y); a[2] = f2bf(lo.z); a[3] = f2bf(lo.w);
      a[4] = f2bf(hi.x); a[5] = f2bf(hi.y); a[6] = f2bf(hi.z); a[7] = f2bf(hi.w);
      int u  = s * 4 + kg;
      int sw = (u ^ (m & 7)) * 16;
      bf16x8 b0 = *(const bf16x8*)((const char*)Bs + (m +  0) * 1024 + sw);
      bf16x8 b1 = *(const bf16x8*)((const char*)Bs + (m + 16) * 1024 + sw);
      bf16x8 b2 = *(const bf16x8*)((const char*)Bs + (m + 32) * 1024 + sw);
      bf16x8 b3 = *(const bf16x8*)((const char*)Bs + (m + 48) * 1024 + sw);
      acc0 = __builtin_amdgcn_mfma_f32_16x16x32_bf16(a, b0, acc0, 0, 0, 0);
      acc1 = __builtin_amdgcn_mfma_f32_16x16x32_bf16(a, b1, acc1, 0, 0, 0);
      acc2 = __builtin_amdgcn_mfma_f32_16x16x32_bf16(a, b2, acc2, 0, 0, 0);
      acc3 = __builtin_amdgcn_mfma_f32_16x16x32_bf16(a, b3, acc3, 0, 0, 0);
    }
  }

  // ---- store partials: part[c][token][col] (fire-and-forget) ----
  float* po = part + ((size_t)c * NTOK + (size_t)t * 128 + w * 16) * 64;
#pragma unroll
  for (int r = 0; r < 4; ++r) {
    int row = kg * 4 + r;
    po[row * 64 + (m +  0)] = acc0[r];
    po[row * 64 + (m + 16)] = acc1[r];
    po[row * 64 + (m + 32)] = acc2[r];
    po[row * 64 + (m + 48)] = acc3[r];
  }
}

// ---------------------------------------------------------------------------
// Kernel 3: reduce 8 K-chunk partials + b1, exact GELU, dot W2, softplus.
// Grid 512, blockIdx = sub*64 + t (matches gemm's XCD swizzle: block for
// tile t lands on XCD t%8 where its partials are L2-resident).
// Block 256 thr: 16 tokens; thread = (token 0..15) x (cid 0..15).
// ---------------------------------------------------------------------------
__global__ __launch_bounds__(256) void delta_ep(const float* __restrict__ part,
                                                const void* __restrict__ b1,
                                                const void* __restrict__ w2,
                                                const void* __restrict__ b2p,
                                                float* __restrict__ delta) {
  int t   = blockIdx.x & 63;
  int sub = blockIdx.x >> 6;                 // 0..7
  int tok = t * 128 + sub * 16 + (threadIdx.x >> 4);
  int cid = threadIdx.x & 15;
  int fb1 = sniff_wave((const unsigned short*)b1, 64);
  int fw2 = sniff_wave((const unsigned short*)w2, 64);
  float y = 0.f;
#pragma unroll
  for (int j = 0; j < 4; ++j) {
    int col = cid + 16 * j;
    float s = 0.f;
#pragma unroll
    for (int c = 0; c < 8; ++c)
      s += part[((size_t)c * NTOK + tok) * 64 + col];
    s += fb1 ? bf2f(b1, col) : ((const float*)b1)[col];
    float g = 0.5f * s * (1.0f + erff(s * 0.70710678118654752f));  // exact GELU
    y += g * (fw2 ? bf2f(w2, col) : ((const float*)w2)[col]);
  }
#pragma unroll
  for (int off = 1; off <= 8; off <<= 1) y += __shfl_xor(y, off, 64);
  if (cid == 0) {
    float x = y + decode_b2(b2p);
    float d = (x > 20.0f) ? x : log1pf(expf(x));  // softplus
    delta[tok] = d;
  }
}

// ---------------------------------------------------------------------------
// Kernel 4: causal EMA, gate, field, mean. OUTPUT IS FLOAT32 (mixed tuple
// (bf16,bf16,f32) concatenated by harness -> numpy-promoted f32).
// ---------------------------------------------------------------------------
__global__ __launch_bounds__(256) void ema_out(const float* __restrict__ delta,
                                               const void* __restrict__ lamp,
                                               float* __restrict__ out) {
  int b    = threadIdx.x >> 6;   // batch 0..3
  int lane = threadIdx.x & 63;
  const float alpha = 0.9f;
  float d[32];
  const float* dp = delta + b * SEQ + lane * 32;
  float beta = 0.f, lsum = 0.f;
#pragma unroll
  for (int i = 0; i < 32; ++i) {
    d[i] = dp[i];
    lsum += d[i];
    beta = alpha * beta + 0.1f * d[i];
  }
  float accA = 0.03433683820292512f;  // 0.9^32
  float accB = beta;
  for (int off = 1; off < 64; off <<= 1) {
    float uA = __shfl_up(accA, off, 64);
    float uB = __shfl_up(accB, off, 64);
    if (lane >= off) {
      accB = accB + accA * uB;  // cur o prev
      accA = accA * uA;
    }
  }
  float prev = __shfl_up(accB, 1, 64);
  float h = (lane == 0) ? 0.f : prev;  // carry-in state for this chunk
  float lam = decode_lam(lamp);
#pragma unroll
  for (int i = 0; i < 32; ++i) {
    h = alpha * h + 0.1f * d[i];
    float gate = 1.0f / (1.0f + expf(lam * h));  // sigmoid(-lam*h)
    out[b * SEQ + lane * 32 + i]        = gate;
    out[NTOK + b * SEQ + lane * 32 + i] = h;
  }
#pragma unroll
  for (int off = 32; off >= 1; off >>= 1) lsum += __shfl_xor(lsum, off, 64);
  __shared__ float bs[4];
  if (lane == 0) bs[b] = lsum;
  __syncthreads();
  if (threadIdx.x == 0)
    out[2 * NTOK] = (bs[0] + bs[1] + bs[2] + bs[3]) * (1.0f / 8192.0f);
}

// ---------------------------------------------------------------------------
extern "C" void kernel_launch(void* const* d_in, const int* in_sizes, int n_in,
                              void* d_out, int out_size, void* d_ws, size_t ws_size,
                              hipStream_t stream) {
  const void* hidden = d_in[0];  // [4,2048,4096]
  const void* Wf     = d_in[1];  // [16,4096]
  const void* W1     = d_in[2];  // [64,4112]
  const void* b1     = d_in[3];  // [64]
  const void* W2     = d_in[4];  // [1,64]
  const void* b2     = d_in[5];  // [1]
  const void* lam    = d_in[6];  // [1]
  float* out = (float*)d_out;    // 16385 f32 (gate 8192 | field 8192 | mean 1)

  // ws: [0, 512K) W1eff bf16, [512K, +32K) delta f32, then part f32
  // [8][8192][64] = 16 MB.
  char* ws = (char*)d_ws;
  short* W1eff = (short*)ws;
  float* delta = (float*)(ws + (size_t)64 * D_MODEL * 2);
  float* part  = (float*)(ws + (size_t)64 * D_MODEL * 2 + NTOK * 4);

  fold_w1<<<64, 256, 0, stream>>>(W1, Wf, W1eff);
  gemm_part<<<512, 512, 0, stream>>>(hidden, W1eff, part);
  delta_ep<<<512, 256, 0, stream>>>(part, b1, W2, b2, delta);
  ema_out<<<1, 256, 0, stream>>>(delta, lam, out);
}

// Round 5
// 227.225 us; speedup vs baseline: 1.0914x; 1.0157x over previous
//
#include <hip/hip_runtime.h>
#include <hip/hip_bf16.h>

#define D_MODEL 4096
#define NTOK    8192   // B*S = 4*2048
#define SEQ     2048

typedef short bf16x8 __attribute__((ext_vector_type(8)));  // 8 bf16 in 4 VGPRs
typedef float f32x4  __attribute__((ext_vector_type(4)));

__device__ __forceinline__ short f2bf(float x) {
  __hip_bfloat16 h = __float2bfloat16(x);
  return *reinterpret_cast<short*>(&h);
}
__device__ __forceinline__ float bfs2f(unsigned short u) {
  unsigned int x = ((unsigned int)u) << 16;
  float f;
  __builtin_memcpy(&f, &x, 4);
  return f;
}
__device__ __forceinline__ float bf2f(const void* p, size_t i) {
  return bfs2f(((const unsigned short*)p)[i]);
}

// Async global->LDS, 16B per lane. LDS dest is the WAVE-UNIFORM base
// (HW adds lane*16); global src is per-lane (guide m104/m173).
__device__ __forceinline__ void gload_lds16(const void* g, void* l) {
  __builtin_amdgcn_global_load_lds(
      (__attribute__((address_space(1))) void*)(g),
      (__attribute__((address_space(3))) void*)(l), 16, 0, 0);
}

// ---------------------------------------------------------------------------
// Wave-level dtype sniff (confirmed: hidden=bf16, weights=f32; kept for
// robustness). Returns 1 -> bf16[], 0 -> float[]. Wave-uniform result.
// ---------------------------------------------------------------------------
__device__ __forceinline__ int sniff_wave(const unsigned short* p, int n) {
  int lane = threadIdx.x & 63;
  int S = n / 2 < 64 ? n / 2 : 64;
  bool act = lane < S;
  unsigned short ve = 0, vo = 0;
  if (act) { ve = p[2 * lane]; vo = p[2 * lane + 1]; }
  int ee = (ve >> 7) & 0xFF, eo = (vo >> 7) & 0xFF;
  bool ve_band   = (ve == 0) || (ve == 0x8000) || (ee >= 96 && ee <= 141);
  bool vo_bandnz = (vo != 0) && (vo != 0x8000) && (eo >= 96 && eo <= 141);
  int zp = __popcll(__ballot(act && ve == 0 && vo == 0));
  int ob = __popcll(__ballot(act && ve == 0 && vo_bandnz));
  int eb = __popcll(__ballot(act && ve_band));
  if (zp == S) return 1;
  if (4 * ob >= 3 * S) return 0;   // f32 storage of bf16-rounded values
  if (4 * eb >= 3 * S) return 1;   // true bf16
  return 0;                        // raw f32
}

__device__ __forceinline__ float decode_lam(const void* lamp) {
  unsigned short l0 = *(const unsigned short*)lamp;
  int le = (l0 >> 7) & 0xFF;
  if (l0 != 0 && l0 != 0x8000 && le >= 96 && le <= 141)
    return bfs2f(l0);
  return *(const float*)lamp;
}
__device__ __forceinline__ float decode_b2(const void* p) {
  unsigned short c0 = *(const unsigned short*)p;
  int ce = (c0 >> 7) & 0xFF;
  if (c0 == 0) return 0.0f;
  if (c0 != 0x8000 && ce >= 96 && ce <= 141)
    return bfs2f(c0);
  return *(const float*)p;
}

// ---------------------------------------------------------------------------
// Kernel 1: fold W_fiber into W1 -> W1_eff[64][4096] bf16 (vectorized).
// ---------------------------------------------------------------------------
__global__ __launch_bounds__(256) void fold_w1(const void* __restrict__ W1v,
                                               const void* __restrict__ Wfv,
                                               short* __restrict__ W1eff) {
  int n = blockIdx.x;  // 0..63
  int fw1 = sniff_wave((const unsigned short*)W1v, 64 * 4112);
  int fwf = sniff_wave((const unsigned short*)Wfv, 16 * D_MODEL);
  __shared__ float w1b[16];
  if (threadIdx.x < 16) {
    size_t idx = (size_t)n * 4112 + 4096 + threadIdx.x;
    w1b[threadIdx.x] = fw1 ? bf2f(W1v, idx) : ((const float*)W1v)[idx];
  }
  __syncthreads();
  for (int it = 0; it < 4; ++it) {
    int k0 = it * 1024 + threadIdx.x * 4;
    size_t idx = (size_t)n * 4112 + k0;
    float v0, v1, v2, v3;
    if (fw1) {
      ushort4 u = *(const ushort4*)((const unsigned short*)W1v + idx);
      v0 = bfs2f(u.x); v1 = bfs2f(u.y); v2 = bfs2f(u.z); v3 = bfs2f(u.w);
    } else {
      float4 f = *(const float4*)((const float*)W1v + idx);
      v0 = f.x; v1 = f.y; v2 = f.z; v3 = f.w;
    }
#pragma unroll
    for (int f = 0; f < 16; ++f) {
      size_t wi = (size_t)f * D_MODEL + k0;
      float w0, w1_, w2_, w3_;
      if (fwf) {
        ushort4 u = *(const ushort4*)((const unsigned short*)Wfv + wi);
        w0 = bfs2f(u.x); w1_ = bfs2f(u.y); w2_ = bfs2f(u.z); w3_ = bfs2f(u.w);
      } else {
        float4 fv = *(const float4*)((const float*)Wfv + wi);
        w0 = fv.x; w1_ = fv.y; w2_ = fv.z; w3_ = fv.w;
      }
      float s = w1b[f];
      v0 += s * w0; v1 += s * w1_; v2 += s * w2_; v3 += s * w3_;
    }
    ushort4 o;
    o.x = (unsigned short)f2bf(v0); o.y = (unsigned short)f2bf(v1);
    o.z = (unsigned short)f2bf(v2); o.w = (unsigned short)f2bf(v3);
    *(ushort4*)(W1eff + (size_t)n * D_MODEL + k0) = o;
  }
}

// ---------------------------------------------------------------------------
// Kernel 2: split-K GEMM partials with FILL-SHAPED A reads.
// Grid 1024 = t*8 + c (t = 64-token tile 0..127, c = K-chunk 0..7 -> XCD=c,
// all 8 chunk column-offsets co-resident: full HBM channel coverage).
// Block 256 thr (4 waves), wave w owns rows [t*64 + w*16, +16).
// A path (the R4-B mechanism, which runs at fill speed): each wave issues
// 16x global_load_lds(16B/lane) — ONE CONTIGUOUS 1 KB row-slice per
// instruction (lanes XOR-permuted within the row: unit lane^(row&7) -> LDS
// slot lane, so the bank swizzle rides on the coalesced source). LDS dest
// linear. No 8KB-strided 64B scatter anywhere.
// No barriers: each wave reads only its own strip; a single
// s_waitcnt vmcnt(0) replaces __syncthreads.
// B: direct 16B/lane loads from W1eff (512 KB, L2-resident) inside the
// k-loop — no barrier stops the compiler from pipelining them.
// ds_read_b128 A-frags: bank-quad = ((s*4+kg)^(m&7))&7 -> 2 lanes/bank
// (free, m136).
// MFMA 16x16x32 bf16: A[m=lane&15][k=8*(lane>>4)+j]; C: col=lane&15,
// row=(lane>>4)*4+reg (m89/m91-verified, unchanged from passing rounds).
// ---------------------------------------------------------------------------
__global__ __launch_bounds__(256, 2) void gemm_part(const void* __restrict__ hid,
                                                    const short* __restrict__ B_,
                                                    float* __restrict__ part) {
  int t = blockIdx.x >> 3;          // M-tile 0..127 (64 rows each)
  int c = blockIdx.x & 7;           // K-chunk 0..7 (XCD = c)
  int w    = threadIdx.x >> 6;      // wave 0..3 = 16-row strip
  int lane = threadIdx.x & 63;
  int m = lane & 15, kg = lane >> 4;

  __shared__ short As[64 * 512];    // 64 KB: row-major 1KB rows, unit-XOR swz

  int fhid = sniff_wave((const unsigned short*)hid, NTOK * D_MODEL);

  f32x4 acc0 = {0.f, 0.f, 0.f, 0.f};
  f32x4 acc1 = acc0, acc2 = acc0, acc3 = acc0;

  const short* Bp = B_ + (size_t)m * D_MODEL + c * 512 + kg * 8;  // +nc*16*D_MODEL

  if (fhid) {  // hidden bf16 (confirmed path)
    // ---- stage own strip: 16 instrs, each one full 1 KB row-slice ----
#pragma unroll
    for (int i = 0; i < 16; ++i) {
      int n = w * 16 + i;           // strip row 0..63 (wave-uniform)
      const char* src = (const char*)hid +
          ((size_t)(t * 64 + n) * D_MODEL + c * 512) * 2 +
          ((lane ^ (n & 7)) * 16);
      gload_lds16(src, (char*)As + n * 1024);
    }
    asm volatile("s_waitcnt vmcnt(0)" ::: "memory");  // own stages done
#pragma unroll
    for (int s = 0; s < 16; ++s) {
      int u  = s * 4 + kg;                        // logical 16B unit 0..63
      int row = w * 16 + m;
      bf16x8 a = *(const bf16x8*)((const char*)As + row * 1024 +
                                  ((u ^ (m & 7)) * 16));
      bf16x8 b0 = *(const bf16x8*)(Bp + (size_t)0 * 16 * D_MODEL + s * 32);
      bf16x8 b1 = *(const bf16x8*)(Bp + (size_t)1 * 16 * D_MODEL + s * 32);
      bf16x8 b2 = *(const bf16x8*)(Bp + (size_t)2 * 16 * D_MODEL + s * 32);
      bf16x8 b3 = *(const bf16x8*)(Bp + (size_t)3 * 16 * D_MODEL + s * 32);
      acc0 = __builtin_amdgcn_mfma_f32_16x16x32_bf16(a, b0, acc0, 0, 0, 0);
      acc1 = __builtin_amdgcn_mfma_f32_16x16x32_bf16(a, b1, acc1, 0, 0, 0);
      acc2 = __builtin_amdgcn_mfma_f32_16x16x32_bf16(a, b2, acc2, 0, 0, 0);
      acc3 = __builtin_amdgcn_mfma_f32_16x16x32_bf16(a, b3, acc3, 0, 0, 0);
    }
  } else {     // hidden f32 fallback (correctness path, demand loads)
    const float* Ap = (const float*)hid +
        (size_t)(t * 64 + w * 16 + m) * D_MODEL + c * 512 + kg * 8;
    for (int s = 0; s < 16; ++s) {
      float4 lo = *(const float4*)(Ap + s * 32);
      float4 hi = *(const float4*)(Ap + s * 32 + 4);
      bf16x8 a;
      a[0] = f2bf(lo.x); a[1] = f2bf(lo.y); a[2] = f2bf(lo.z); a[3] = f2bf(lo.w);
      a[4] = f2bf(hi.x); a[5] = f2bf(hi.y); a[6] = f2bf(hi.z); a[7] = f2bf(hi.w);
      bf16x8 b0 = *(const bf16x8*)(Bp + (size_t)0 * 16 * D_MODEL + s * 32);
      bf16x8 b1 = *(const bf16x8*)(Bp + (size_t)1 * 16 * D_MODEL + s * 32);
      bf16x8 b2 = *(const bf16x8*)(Bp + (size_t)2 * 16 * D_MODEL + s * 32);
      bf16x8 b3 = *(const bf16x8*)(Bp + (size_t)3 * 16 * D_MODEL + s * 32);
      acc0 = __builtin_amdgcn_mfma_f32_16x16x32_bf16(a, b0, acc0, 0, 0, 0);
      acc1 = __builtin_amdgcn_mfma_f32_16x16x32_bf16(a, b1, acc1, 0, 0, 0);
      acc2 = __builtin_amdgcn_mfma_f32_16x16x32_bf16(a, b2, acc2, 0, 0, 0);
      acc3 = __builtin_amdgcn_mfma_f32_16x16x32_bf16(a, b3, acc3, 0, 0, 0);
    }
  }

  // ---- store partials: part[c][token][col] (fire-and-forget) ----
  float* po = part + ((size_t)c * NTOK + (size_t)t * 64 + w * 16) * 64;
#pragma unroll
  for (int r = 0; r < 4; ++r) {
    int row = kg * 4 + r;
    po[row * 64 + (m +  0)] = acc0[r];
    po[row * 64 + (m + 16)] = acc1[r];
    po[row * 64 + (m + 32)] = acc2[r];
    po[row * 64 + (m + 48)] = acc3[r];
  }
}

// ---------------------------------------------------------------------------
// Kernel 3: reduce 8 K-chunk partials + b1, exact GELU, dot W2, softplus.
// Grid 512, block 256 thr: 16 tokens; thread = (token 0..15) x (cid 0..15).
// ---------------------------------------------------------------------------
__global__ __launch_bounds__(256) void delta_ep(const float* __restrict__ part,
                                                const void* __restrict__ b1,
                                                const void* __restrict__ w2,
                                                const void* __restrict__ b2p,
                                                float* __restrict__ delta) {
  int tok = blockIdx.x * 16 + (threadIdx.x >> 4);
  int cid = threadIdx.x & 15;
  int fb1 = sniff_wave((const unsigned short*)b1, 64);
  int fw2 = sniff_wave((const unsigned short*)w2, 64);
  float y = 0.f;
#pragma unroll
  for (int j = 0; j < 4; ++j) {
    int col = cid + 16 * j;
    float s = 0.f;
#pragma unroll
    for (int c = 0; c < 8; ++c)
      s += part[((size_t)c * NTOK + tok) * 64 + col];
    s += fb1 ? bf2f(b1, col) : ((const float*)b1)[col];
    float g = 0.5f * s * (1.0f + erff(s * 0.70710678118654752f));  // exact GELU
    y += g * (fw2 ? bf2f(w2, col) : ((const float*)w2)[col]);
  }
#pragma unroll
  for (int off = 1; off <= 8; off <<= 1) y += __shfl_xor(y, off, 64);
  if (cid == 0) {
    float x = y + decode_b2(b2p);
    float d = (x > 20.0f) ? x : log1pf(expf(x));  // softplus
    delta[tok] = d;
  }
}

// ---------------------------------------------------------------------------
// Kernel 4: causal EMA, gate, field, mean. OUTPUT IS FLOAT32 (mixed tuple
// (bf16,bf16,f32) concatenated by harness -> numpy-promoted f32).
// ---------------------------------------------------------------------------
__global__ __launch_bounds__(256) void ema_out(const float* __restrict__ delta,
                                               const void* __restrict__ lamp,
                                               float* __restrict__ out) {
  int b    = threadIdx.x >> 6;   // batch 0..3
  int lane = threadIdx.x & 63;
  const float alpha = 0.9f;
  float d[32];
  const float* dp = delta + b * SEQ + lane * 32;
  float beta = 0.f, lsum = 0.f;
#pragma unroll
  for (int i = 0; i < 32; ++i) {
    d[i] = dp[i];
    lsum += d[i];
    beta = alpha * beta + 0.1f * d[i];
  }
  float accA = 0.03433683820292512f;  // 0.9^32
  float accB = beta;
  for (int off = 1; off < 64; off <<= 1) {
    float uA = __shfl_up(accA, off, 64);
    float uB = __shfl_up(accB, off, 64);
    if (lane >= off) {
      accB = accB + accA * uB;  // cur o prev
      accA = accA * uA;
    }
  }
  float prev = __shfl_up(accB, 1, 64);
  float h = (lane == 0) ? 0.f : prev;  // carry-in state for this chunk
  float lam = decode_lam(lamp);
#pragma unroll
  for (int i = 0; i < 32; ++i) {
    h = alpha * h + 0.1f * d[i];
    float gate = 1.0f / (1.0f + expf(lam * h));  // sigmoid(-lam*h)
    out[b * SEQ + lane * 32 + i]        = gate;
    out[NTOK + b * SEQ + lane * 32 + i] = h;
  }
#pragma unroll
  for (int off = 32; off >= 1; off >>= 1) lsum += __shfl_xor(lsum, off, 64);
  __shared__ float bs[4];
  if (lane == 0) bs[b] = lsum;
  __syncthreads();
  if (threadIdx.x == 0)
    out[2 * NTOK] = (bs[0] + bs[1] + bs[2] + bs[3]) * (1.0f / 8192.0f);
}

// ---------------------------------------------------------------------------
extern "C" void kernel_launch(void* const* d_in, const int* in_sizes, int n_in,
                              void* d_out, int out_size, void* d_ws, size_t ws_size,
                              hipStream_t stream) {
  const void* hidden = d_in[0];  // [4,2048,4096]
  const void* Wf     = d_in[1];  // [16,4096]
  const void* W1     = d_in[2];  // [64,4112]
  const void* b1     = d_in[3];  // [64]
  const void* W2     = d_in[4];  // [1,64]
  const void* b2     = d_in[5];  // [1]
  const void* lam    = d_in[6];  // [1]
  float* out = (float*)d_out;    // 16385 f32 (gate 8192 | field 8192 | mean 1)

  // ws: [0, 512K) W1eff bf16, [512K, +32K) delta f32, then part f32
  // [8][8192][64] = 16 MB.
  char* ws = (char*)d_ws;
  short* W1eff = (short*)ws;
  float* delta = (float*)(ws + (size_t)64 * D_MODEL * 2);
  float* part  = (float*)(ws + (size_t)64 * D_MODEL * 2 + NTOK * 4);

  fold_w1<<<64, 256, 0, stream>>>(W1, Wf, W1eff);
  gemm_part<<<1024, 256, 0, stream>>>(hidden, W1eff, part);
  delta_ep<<<512, 256, 0, stream>>>(part, b1, W2, b2, delta);
  ema_out<<<1, 256, 0, stream>>>(delta, lam, out);
}